// Round 10
// baseline (1782.032 us; speedup 1.0000x reference)
//
#include <hip/hip_runtime.h>

typedef _Float16 half8 __attribute__((ext_vector_type(8)));
typedef float floatx4 __attribute__((ext_vector_type(4)));

#define T_STEPS 256
#define BB      16
#define NTH     512
#define W1      8      // h1 ring slots
#define W2      8      // xp2 ring slots

// d_ws layout: weight frag arrays (halves), ring1, ring2, flags
#define WHH0_H  0
#define WIH1_H  65536
#define WHH1_H  131072
#define WIH0_H  196608
#define RING1_H 212992               // 64 groups x 8 slots x 2048 halves (4 KB)
#define RING2_H 1261568              // 64 groups x 8 slots x 8192 halves (16 KB)
#define FLAG_B  10911744             // byte offset of flag region
#define FLAG_BYTES 16384

__device__ __forceinline__ float sig_(float z)  { return __builtin_amdgcn_rcpf(1.f + __expf(-z)); }
__device__ __forceinline__ float tanh_(float z) { return 1.f - 2.f * __builtin_amdgcn_rcpf(1.f + __expf(2.f * z)); }

// Build fp16 MFMA B-fragment arrays.
// Frag index: ((wv*4+gi)*4+ks)*64 + lane ; lane holds W[gi*128+wv*16+(l&15)][ks*32+(l>>4)*8 + j]
__global__ __launch_bounds__(256) void prep_weights(
    const float* __restrict__ w_ih0, const float* __restrict__ w_hh0,
    const float* __restrict__ w_ih1, const float* __restrict__ w_hh1,
    _Float16* __restrict__ wf)
{
    const int idx = blockIdx.x * 256 + threadIdx.x;   // 0..8191
    const int l  = idx & 63;
    const int ks = (idx >> 6) & 3;
    const int gi = (idx >> 8) & 3;
    const int wv = (idx >> 10) & 7;
    const int row = gi * 128 + wv * 16 + (l & 15);
    const int kb  = ks * 32 + (l >> 4) * 8;
#pragma unroll
    for (int j = 0; j < 8; ++j) {
        wf[WHH0_H + idx * 8 + j] = (_Float16)w_hh0[row * 128 + kb + j];
        wf[WIH1_H + idx * 8 + j] = (_Float16)w_ih1[row * 128 + kb + j];
        wf[WHH1_H + idx * 8 + j] = (_Float16)w_hh1[row * 128 + kb + j];
    }
    if (ks == 0) {
        // x-frag convention: lk=0 -> W[0..7]; lk=1 -> 0,0,W[8..13]; lk>=2 -> 0
        const int lk = l >> 4;
        const int oi = ((wv * 4 + gi) * 64 + l) * 8;
#pragma unroll
        for (int j = 0; j < 8; ++j) {
            float v = 0.f;
            if (lk == 0)                v = w_ih0[row * 14 + j];
            else if (lk == 1 && j >= 2) v = w_ih0[row * 14 + 6 + j];
            wf[WIH0_H + oi + j] = (_Float16)v;
        }
    }
}

// read A-frags of h (XOR-swizzled LDS tile [batch][128 units])
#define READFRAG(DSTARR, SRC) do {                                              \
    _Pragma("unroll")                                                           \
    for (int ks = 0; ks < 4; ++ks) {                                            \
        const int off = lrow * 256 + ((ks * 64 + lk * 16) ^ ((lrow & 7) << 4)); \
        DSTARR[ks] = *(const half8*)((const char*)(SRC) + off);                 \
    }                                                                           \
} while (0)

// 3-stage pipeline: role 0 = L1 recurrence (whh0 in LDS), role 1 = xp2 GEMM
// (wih1 in LDS, stateless), role 2 = L2 recurrence (whh1 in LDS). 192 blocks.
__global__ void __launch_bounds__(NTH) lstm3_pipe(
    const float* __restrict__ x, const _Float16* __restrict__ wf,
    const float* __restrict__ b_ih0, const float* __restrict__ b_hh0,
    const float* __restrict__ b_ih1, const float* __restrict__ b_hh1,
    const float* __restrict__ w_lin, const float* __restrict__ b_lin,
    float* __restrict__ out, char* __restrict__ wsb)
{
    __shared__ __align__(16) _Float16 wlds[65536];       // 128 KB role-weight, frag-ordered
    __shared__ __align__(16) _Float16 hs[2][BB * 128];   // 8 KB own-layer h history

    const int tid  = threadIdx.x;
    const int l    = tid & 63;
    const int wv   = tid >> 6;
    const int lrow = l & 15;      // A row = batch ; D col = unit
    const int lk   = l >> 4;
    const int g    = blockIdx.x & 63;
    const int role = blockIdx.x >> 6;     // 0 / 1 / 2 (same XCD for a group's trio)
    const int b0   = g * BB;
    const int u    = wv * 16 + lrow;

    _Float16* ring1 = (_Float16*)wsb + RING1_H + (size_t)g * W1 * 2048;
    _Float16* ring2 = (_Float16*)wsb + RING2_H + (size_t)g * W2 * 8192;
    int* fp = (int*)(wsb + FLAG_B) + g * 64;   // stage-A progress
    int* fb = fp + 16;                         // stage-B progress (= ring1 consumed)
    int* fc = fp + 32;                         // stage-C progress (= ring2 consumed)

    // stage role-weight matrix into LDS (one 128 KB matrix per role)
    {
        const int srcoff = (role == 0) ? WHH0_H : (role == 1) ? WIH1_H : WHH1_H;
        const floatx4* src = (const floatx4*)(wf + srcoff);
        floatx4* dst = (floatx4*)wlds;
        for (int i = tid; i < 8192; i += NTH) dst[i] = src[i];
    }
    for (int i = tid; i < 2048; i += NTH) ((unsigned*)hs)[i] = 0u;
    __syncthreads();

    // LDS frag base: frag(gi,ks) at wbase + (gi*4+ks)*1024 (lane-contiguous b128)
    const char* wbase = (const char*)wlds + (wv * 1024 + l) * 16;

    if (role == 0) {
        // ================= stage A: layer-1 recurrence =================
        const half8* wsf = (const half8*)wf;
        half8 wih0f[4];
#pragma unroll
        for (int gi = 0; gi < 4; ++gi)
            wih0f[gi] = wsf[WIH0_H / 8 + (wv * 4 + gi) * 64 + l];
        float bias1[4];
#pragma unroll
        for (int gi = 0; gi < 4; ++gi) {
            const int col = gi * 128 + wv * 16 + lrow;
            bias1[gi] = b_ih0[col] + b_hh0[col];
        }
        float c1[4] = {0.f, 0.f, 0.f, 0.f};
        const int coff = (lk == 1) ? 6 : 0;
        const float* xp = x + (size_t)(b0 + lrow) * (T_STEPS * 14) + coff;
        float xr[8];
#pragma unroll
        for (int j = 0; j < 8; ++j) xr[j] = xp[j];
        int seen_b = 0;

        for (int t = 0; t < T_STEPS; ++t) {
            const int cur = t & 1, prv = cur ^ 1;
            half8 xh;
#pragma unroll
            for (int j = 0; j < 8; ++j) xh[j] = (_Float16)xr[j];

            half8 h1p[4];
            READFRAG(h1p, hs[prv]);

            floatx4 acc[4];
#pragma unroll
            for (int gi = 0; gi < 4; ++gi) {
                acc[gi] = (floatx4){bias1[gi], bias1[gi], bias1[gi], bias1[gi]};
                acc[gi] = __builtin_amdgcn_mfma_f32_16x16x32_f16(xh, wih0f[gi], acc[gi], 0, 0, 0);
#pragma unroll
                for (int ks = 0; ks < 4; ++ks) {
                    const half8 wb = *(const half8*)(wbase + (gi * 4 + ks) * 1024);
                    acc[gi] = __builtin_amdgcn_mfma_f32_16x16x32_f16(h1p[ks], wb, acc[gi], 0, 0, 0);
                }
            }

            // ring1 credit: B must have consumed slot t&7 (B done step t-8)
            if (t >= W1) {
                while (seen_b < t - (W1 - 1)) {
                    seen_b = __hip_atomic_load(fb, __ATOMIC_RELAXED, __HIP_MEMORY_SCOPE_AGENT);
                    if (seen_b < t - (W1 - 1)) __builtin_amdgcn_s_sleep(2);
                }
            }

            {
                char* hwr = (char*)hs[cur];
                _Float16* rt = ring1 + (size_t)(t & (W1 - 1)) * 2048;
#pragma unroll
                for (int r = 0; r < 4; ++r) {
                    const float ig = sig_(acc[0][r]);
                    const float fg = sig_(acc[1][r]);
                    const float gg = tanh_(acc[2][r]);
                    const float og = sig_(acc[3][r]);
                    c1[r] = fg * c1[r] + ig * gg;
                    const float hv = og * tanh_(c1[r]);
                    const int b = lk * 4 + r;
                    const _Float16 hh = (_Float16)hv;
                    *(_Float16*)(hwr + b * 256 + ((u * 2) ^ ((b & 7) << 4))) = hh;
                    rt[b * 128 + u] = hh;
                }
            }

            asm volatile("s_waitcnt vmcnt(0) lgkmcnt(0)" ::: "memory");
            __builtin_amdgcn_s_barrier();
            if (tid == 0)
                __hip_atomic_store(fp, t + 1, __ATOMIC_RELEASE, __HIP_MEMORY_SCOPE_AGENT);
            if (t + 1 < T_STEPS) {
#pragma unroll
                for (int j = 0; j < 8; ++j) xr[j] = xp[(t + 1) * 14 + j];
            }
        }
    } else if (role == 1) {
        // ================= stage B: xp2(t) = wih1 . h1(t) (stateless) =================
        const int toff = lrow * 256 + lk * 16;   // A-frag ks=0 byte offset in ring1 tile
        int seen_p = 0, seen_c = 0;

        for (int t = 0; t < T_STEPS; ++t) {
            while (seen_p < t + 1) {
                seen_p = __hip_atomic_load(fp, __ATOMIC_ACQUIRE, __HIP_MEMORY_SCOPE_AGENT);
                if (seen_p < t + 1) __builtin_amdgcn_s_sleep(2);
            }
            const char* rt = (const char*)ring1 + (size_t)(t & (W1 - 1)) * 4096;
            half8 h1n[4];
#pragma unroll
            for (int ks = 0; ks < 4; ++ks)
                h1n[ks] = *(const half8*)(rt + toff + ks * 64);

            floatx4 acc[4];
#pragma unroll
            for (int gi = 0; gi < 4; ++gi) {
                acc[gi] = (floatx4){0.f, 0.f, 0.f, 0.f};
#pragma unroll
                for (int ks = 0; ks < 4; ++ks) {
                    const half8 wb = *(const half8*)(wbase + (gi * 4 + ks) * 1024);
                    acc[gi] = __builtin_amdgcn_mfma_f32_16x16x32_f16(h1n[ks], wb, acc[gi], 0, 0, 0);
                }
            }

            // ring2 credit: C must have consumed slot t&7 (C done step t-8)
            if (t >= W2) {
                while (seen_c < t - (W2 - 1)) {
                    seen_c = __hip_atomic_load(fc, __ATOMIC_RELAXED, __HIP_MEMORY_SCOPE_AGENT);
                    if (seen_c < t - (W2 - 1)) __builtin_amdgcn_s_sleep(2);
                }
            }

            _Float16* rt2 = ring2 + (size_t)(t & (W2 - 1)) * 8192;
#pragma unroll
            for (int gi = 0; gi < 4; ++gi)
#pragma unroll
                for (int r = 0; r < 4; ++r)
                    rt2[(lk * 4 + r) * 512 + gi * 128 + u] = (_Float16)acc[gi][r];

            asm volatile("s_waitcnt vmcnt(0) lgkmcnt(0)" ::: "memory");
            __builtin_amdgcn_s_barrier();
            if (tid == 0)
                __hip_atomic_store(fb, t + 1, __ATOMIC_RELEASE, __HIP_MEMORY_SCOPE_AGENT);
        }
    } else {
        // ================= stage C: layer-2 recurrence =================
        float bias2[4];
#pragma unroll
        for (int gi = 0; gi < 4; ++gi) {
            const int col = gi * 128 + wv * 16 + lrow;
            bias2[gi] = b_ih1[col] + b_hh1[col];
        }
        float c2[4] = {0.f, 0.f, 0.f, 0.f};
        int seen_b = 0;

        for (int t = 0; t < T_STEPS; ++t) {
            const int cur = t & 1, prv = cur ^ 1;
            while (seen_b < t + 1) {
                seen_b = __hip_atomic_load(fb, __ATOMIC_ACQUIRE, __HIP_MEMORY_SCOPE_AGENT);
                if (seen_b < t + 1) __builtin_amdgcn_s_sleep(2);
            }
            // issue xp2 scalar loads early; consumed after the MFMAs
            const _Float16* rt2 = ring2 + (size_t)(t & (W2 - 1)) * 8192;
            _Float16 xv[16];
#pragma unroll
            for (int gi = 0; gi < 4; ++gi)
#pragma unroll
                for (int r = 0; r < 4; ++r)
                    xv[gi * 4 + r] = rt2[(lk * 4 + r) * 512 + gi * 128 + u];

            half8 h2p[4];
            READFRAG(h2p, hs[prv]);

            floatx4 acc[4];
#pragma unroll
            for (int gi = 0; gi < 4; ++gi) {
                acc[gi] = (floatx4){bias2[gi], bias2[gi], bias2[gi], bias2[gi]};
#pragma unroll
                for (int ks = 0; ks < 4; ++ks) {
                    const half8 wb = *(const half8*)(wbase + (gi * 4 + ks) * 1024);
                    acc[gi] = __builtin_amdgcn_mfma_f32_16x16x32_f16(h2p[ks], wb, acc[gi], 0, 0, 0);
                }
            }

            {
                char* hwr = (char*)hs[cur];
#pragma unroll
                for (int r = 0; r < 4; ++r) {
                    const float ig = sig_(acc[0][r] + (float)xv[r]);
                    const float fg = sig_(acc[1][r] + (float)xv[4 + r]);
                    const float gg = tanh_(acc[2][r] + (float)xv[8 + r]);
                    const float og = sig_(acc[3][r] + (float)xv[12 + r]);
                    c2[r] = fg * c2[r] + ig * gg;
                    const float hv = og * tanh_(c2[r]);
                    const int b = lk * 4 + r;
                    *(_Float16*)(hwr + b * 256 + ((u * 2) ^ ((b & 7) << 4))) = (_Float16)hv;
                }
            }

            asm volatile("s_waitcnt lgkmcnt(0)" ::: "memory");
            __builtin_amdgcn_s_barrier();
            if (tid == 0)
                __hip_atomic_store(fc, t + 1, __ATOMIC_RELAXED, __HIP_MEMORY_SCOPE_AGENT);
        }

        // epilogue: out[b] = h2(255)[b] . w_lin + b_lin ; h2(255) in hs[1]
        if (tid < 64) {
            const char* hb = (const char*)hs[1];
            const int bb = tid & 15, q = tid >> 4;
            float acc = 0.f;
#pragma unroll
            for (int j5 = 0; j5 < 32; ++j5) {
                const int j = q * 32 + j5;
                acc += w_lin[j] * (float)(*(const _Float16*)(hb + bb * 256 + ((j * 2) ^ ((bb & 7) << 4))));
            }
            acc += __shfl_xor(acc, 16, 64);
            acc += __shfl_xor(acc, 32, 64);
            if (q == 0) out[b0 + bb] = acc + b_lin[0];
        }
    }
}

extern "C" void kernel_launch(void* const* d_in, const int* in_sizes, int n_in,
                              void* d_out, int out_size, void* d_ws, size_t ws_size,
                              hipStream_t stream) {
    (void)in_sizes; (void)n_in; (void)ws_size; (void)out_size;
    const float* x     = (const float*)d_in[0];
    const float* w_ih0 = (const float*)d_in[1];
    const float* w_hh0 = (const float*)d_in[2];
    const float* b_ih0 = (const float*)d_in[3];
    const float* b_hh0 = (const float*)d_in[4];
    const float* w_ih1 = (const float*)d_in[5];
    const float* w_hh1 = (const float*)d_in[6];
    const float* b_ih1 = (const float*)d_in[7];
    const float* b_hh1 = (const float*)d_in[8];
    const float* w_lin = (const float*)d_in[9];
    const float* b_lin = (const float*)d_in[10];
    float* out = (float*)d_out;
    char* wsb = (char*)d_ws;

    hipMemsetAsync(wsb + FLAG_B, 0, FLAG_BYTES, stream);
    hipLaunchKernelGGL(prep_weights, dim3(32), dim3(256), 0, stream,
                       w_ih0, w_hh0, w_ih1, w_hh1, (_Float16*)d_ws);
    hipLaunchKernelGGL(lstm3_pipe, dim3(192), dim3(NTH), 0, stream,
                       x, (const _Float16*)d_ws, b_ih0, b_hh0, b_ih1, b_hh1,
                       w_lin, b_lin, out, wsb);
}